// Round 19
// baseline (265.416 us; speedup 1.0000x reference)
//
#include <hip/hip_runtime.h>
#include <hip/hip_bf16.h>
#include <math.h>

#define B_    4
#define CIN_  256
#define COUT_ 256
#define H_    128
#define W_    128
#define HW_   16384
#define SD_   512
#define HO_   130
#define HU_   260
#define NT_   12

typedef unsigned short ushort_t;
typedef __attribute__((ext_vector_type(8))) short short8;
typedef __attribute__((ext_vector_type(4))) float f32x4;

__device__ inline ushort_t f2bf_(float v) {
  union { float f; unsigned u; } x; x.f = v;
  unsigned r = x.u + 0x7fffu + ((x.u >> 16) & 1u);
  return (ushort_t)(r >> 16);
}
__device__ inline void gll16(const ushort_t* g, ushort_t* l) {
  __builtin_amdgcn_global_load_lds(
      (const __attribute__((address_space(1))) unsigned int*)g,
      (__attribute__((address_space(3))) unsigned int*)l, 16, 0, 0);
}

// ---------------- K1: modulation s[b][cin] ----------------
__global__ __launch_bounds__(256) void k_mod(const float* __restrict__ style,
                                             const float* __restrict__ mw,
                                             const float* __restrict__ mb,
                                             float* __restrict__ s) {
  int wid  = (blockIdx.x * blockDim.x + threadIdx.x) >> 6;
  int lane = threadIdx.x & 63;
  int b = wid >> 8, ci = wid & 255;
  const float* st = style + b * SD_;
  const float* w  = mw + ci * SD_;
  float acc = 0.f;
  for (int k = lane; k < SD_; k += 64) acc += st[k] * w[k];
  for (int off = 32; off; off >>= 1) acc += __shfl_down(acc, off);
  if (lane == 0) s[wid] = acc * 0.044194173824159216f + mb[ci];
}

// ---------------- K2: demod[b][cout] ----------------
__global__ __launch_bounds__(256) void k_demod(const float* __restrict__ weight,
                                               const float* __restrict__ s,
                                               float* __restrict__ demod) {
  int wid  = (blockIdx.x * blockDim.x + threadIdx.x) >> 6;
  int lane = threadIdx.x & 63;
  int b = wid >> 8, co = wid & 255;
  const float* wrow = weight + co * CIN_ * 9;
  const float* sb   = s + b * CIN_;
  float acc = 0.f;
  for (int e = lane; e < CIN_ * 9; e += 64) {
    float p = wrow[e] * sb[e / 9];
    acc += p * p;
  }
  for (int off = 32; off; off >>= 1) acc += __shfl_down(acc, off);
  if (lane == 0) demod[wid] = rsqrtf(acc + 1e-8f);
}

// ---------------- K2b: weight pre-transform (bf16) ----------------
__global__ __launch_bounds__(256) void k_prep_w(const float* __restrict__ W,
                                                ushort_t* __restrict__ Wth) {
  int idx = blockIdx.x * 256 + threadIdx.x;
  if (idx >= 589824) return;
  int j  = idx & 7;
  int co = (idx >> 3) & 127;
  int kc = (idx >> 10) & 3;
  int kb = (idx >> 12) & 7;
  int cb = (idx >> 15) & 1;
  int t  = idx >> 16;
  int ci  = kb * 32 + kc * 8 + j;
  int cog = cb * 128 + co;
  Wth[idx] = f2bf_(W[(cog * CIN_ + ci) * 9 + t]);
}

// ---------------- K2c: X pre-transform (pure bf16) ----------------
__global__ __launch_bounds__(256) void k_prep_x(const float* __restrict__ input,
                                                const float* __restrict__ s,
                                                ushort_t* __restrict__ Xt,
                                                float* __restrict__ zp) {
  int b = blockIdx.z, cb = blockIdx.y, px0 = blockIdx.x * 64;
  int tid = threadIdx.x;
  __shared__ float T[64 * 131];
  __shared__ float sSh[128];
  if (tid < 128) sSh[tid] = s[b * 256 + cb * 128 + tid];
  if (blockIdx.x == 0 && blockIdx.y == 0 && blockIdx.z == 0 && tid < 4)
    zp[tid] = 0.f;
  __syncthreads();
  const float* inb = input + (size_t)(b * 256 + cb * 128) * HW_ + px0;
#pragma unroll
  for (int r2 = 0; r2 < 32; ++r2) {
    int idx = r2 * 256 + tid;
    int ci = idx >> 6, p = idx & 63;
    T[p * 131 + ci] = inb[(size_t)ci * HW_ + p] * sSh[ci];
  }
  __syncthreads();
  ushort_t* xb = Xt + (size_t)b * HW_ * 256 + cb * 128;
#pragma unroll
  for (int r2 = 0; r2 < 16; ++r2) {
    int u = r2 * 256 + tid;
    int cp = u & 63, p = u >> 6;
    float v0 = T[p * 131 + 2 * cp], v1 = T[p * 131 + 2 * cp + 1];
    unsigned pk = (unsigned)f2bf_(v0) | ((unsigned)f2bf_(v1) << 16);
    *(unsigned*)(xb + ((size_t)(px0 + p)) * 256 + cp * 2) = pk;
  }
}

// ---------------- K3: modulated conv via MFMA (X bf16, W bf16; 4 blocks/CU) ----------------
#define XCELLS 864
#define XROUNDS 4
#define XBUFU  1024

__global__ __launch_bounds__(256, 4) void k_conv_mfma(
    const ushort_t* __restrict__ Xt, const ushort_t* __restrict__ Wth,
    const float* __restrict__ demod, const float* __restrict__ bias,
    const ushort_t* __restrict__ zpg, float* __restrict__ out1) {
  const int tid = threadIdx.x;
  const int b = blockIdx.z >> 1, cb = blockIdx.z & 1;
  const int y0 = blockIdx.y * 10, x0 = blockIdx.x * 16;
  const int lane = tid & 63, lr = lane & 15, kcc = lane >> 4;
  const int w = tid >> 6;

  __shared__ __align__(16) ushort_t XL[2][XBUFU * 8];

  f32x4 acc[2][10];
#pragma unroll
  for (int i = 0; i < 2; ++i)
#pragma unroll
    for (int jj = 0; jj < 10; ++jj) acc[i][jj] = (f32x4)0.f;

  const ushort_t* gsrc[XROUNDS];
  bool okr[XROUNDS];
#pragma unroll
  for (int r = 0; r < XROUNDS; ++r) {
    int u = r * 256 + tid;
    const ushort_t* p = zpg;
    bool ok = false;
    if (u < XCELLS) {
      int kc = u / 216, cell = u - kc * 216;
      int hy = cell / 18, hx = cell - hy * 18;
      int iy = y0 + hy - 2, ix = x0 + hx - 2;
      if ((unsigned)iy < 128u && (unsigned)ix < 128u) {
        p = Xt + (((size_t)b * HW_ + iy * W_ + ix) << 8) + kc * 8;
        ok = true;
      }
    }
    gsrc[r] = p; okr[r] = ok;
  }

  auto stage = [&](int kb, int bufsel) {
    ushort_t* lb = &XL[bufsel][(size_t)tid * 8];
#pragma unroll
    for (int r = 0; r < XROUNDS; ++r) {
      const ushort_t* g = okr[r] ? gsrc[r] + kb * 32 : zpg;
      gll16(g, lb + r * 2048);
    }
  };

  stage(0, 0);
  __syncthreads();

  for (int kb = 0; kb < 8; ++kb) {
    const ushort_t* Xc = &XL[kb & 1][0];
    const int wbo = cb * 32768 + kb * 4096 + kcc * 1024 + (w * 32 + lr) * 8;
#pragma unroll
    for (int kx = 0; kx < 3; ++kx) {
      short8 ah[3][2];
#pragma unroll
      for (int ky = 0; ky < 3; ++ky) {
        const ushort_t* wh = Wth + wbo + (ky * 3 + kx) * 65536;
        ah[ky][0] = *(const short8*)wh;
        ah[ky][1] = *(const short8*)(wh + 128);
      }
      if (kx == 0) {
        __builtin_amdgcn_sched_barrier(0);
        if (kb < 7) stage(kb + 1, (kb & 1) ^ 1);
      }
#pragma unroll
      for (int r = 0; r < 12; ++r) {
        const int c16 = (kcc * 216 + r * 18 + lr + kx) * 8;
        short8 bh = *(const short8*)&Xc[c16];
#pragma unroll
        for (int ky = 0; ky < 3; ++ky) {
          const int bn = r - ky;
          if (bn >= 0 && bn < 10) {
            acc[0][bn] = __builtin_amdgcn_mfma_f32_16x16x32_bf16(ah[ky][0], bh, acc[0][bn], 0, 0, 0);
            acc[1][bn] = __builtin_amdgcn_mfma_f32_16x16x32_bf16(ah[ky][1], bh, acc[1][bn], 0, 0, 0);
          }
        }
      }
    }
    if (kb < 7) __syncthreads();
  }

#pragma unroll
  for (int am = 0; am < 2; ++am) {
#pragma unroll
    for (int r = 0; r < 4; ++r) {
      int cog = cb * 128 + w * 32 + am * 16 + kcc * 4 + r;
      float dm = demod[b * 256 + cog];
      float bv = bias[cog];
      int ox = x0 + lr;
      if (ox < HO_) {
#pragma unroll
        for (int bn = 0; bn < 10; ++bn) {
          int oy = y0 + bn;
          out1[((b * 256 + cog) * HO_ + oy) * HO_ + ox] = acc[am][bn][r] * dm + bv;
        }
      }
    }
  }
}

// ---------------- K4: fused FIR (R17 version: 2-buffer overlay, 40960B, 4 blocks/CU) ----------------
#define I1S 132
#define I2S 260

__global__ __launch_bounds__(256) void k_fir(const float* __restrict__ src,
                                             const float* __restrict__ upf,
                                             const float* __restrict__ dnf,
                                             float* __restrict__ dst) {
  const int plane = blockIdx.y;
  const int y0 = blockIdx.x * 8;
  const int tid = threadIdx.x;

  __shared__ __align__(16) float I1D[26 * I1S];
  __shared__ __align__(16) float B2[26 * I2S];

  float* SD = B2;
  float* I2 = B2;
  float* I1 = I1D;
  float* D  = I1D;

  float fe[6], fo[6], fdt[12];
#pragma unroll
  for (int j = 0; j < 6; ++j) { fe[j] = upf[2 * j] * 2.f; fo[j] = upf[2 * j + 1] * 2.f; }
#pragma unroll
  for (int t = 0; t < NT_; ++t) fdt[t] = dnf[t];
  const float kPos = 1.41421356237309515f, kNeg = 0.28284271247461903f;

  const float* sp = src + (size_t)plane * (HO_ * HO_);
#pragma unroll
  for (int k = 0; k < 3; ++k) {
    int idx = tid + k * 256;
    if (idx < 594) {
      int r = idx / 33, q = idx - 33 * r;
      int gy = y0 - 5 + r;
      int cbase = 4 * q;
      float4 v = make_float4(0.f, 0.f, 0.f, 0.f);
      if ((unsigned)gy < (unsigned)HO_) {
        const float* rp = sp + gy * HO_ + cbase;
        v.x = rp[0];
        v.y = (cbase + 1 < HO_) ? rp[1] : 0.f;
        v.z = (cbase + 2 < HO_) ? rp[2] : 0.f;
        v.w = (cbase + 3 < HO_) ? rp[3] : 0.f;
      }
      *(float4*)&SD[r * 132 + cbase] = v;
    }
  }
  __syncthreads();

  {
    int c = tid & 127, uh = tid >> 7;
    float wv[6];
    if (uh == 0) {
#pragma unroll
      for (int j = 0; j < 6; ++j) wv[j] = SD[j * 132 + c];
#pragma unroll
      for (int lr = 0; lr < 7; ++lr) {
        float a = fo[0]*wv[0] + fo[1]*wv[1] + fo[2]*wv[2] + fo[3]*wv[3] + fo[4]*wv[4] + fo[5]*wv[5];
        int ugl = 2 * y0 - 5 + 2 * lr;
        I1[(2 * lr) * I1S + c] = ((unsigned)ugl < (unsigned)HU_) ? a : 0.f;
        if (lr < 6) {
#pragma unroll
          for (int j = 0; j < 5; ++j) wv[j] = wv[j + 1];
          wv[5] = SD[(lr + 6) * 132 + c];
        }
      }
#pragma unroll
      for (int j = 0; j < 6; ++j) wv[j] = SD[j * 132 + c];
#pragma unroll
      for (int lr = 0; lr < 6; ++lr) {
        float a = fe[0]*wv[0] + fe[1]*wv[1] + fe[2]*wv[2] + fe[3]*wv[3] + fe[4]*wv[4] + fe[5]*wv[5];
        int ugl = 2 * y0 - 4 + 2 * lr;
        I1[(2 * lr + 1) * I1S + c] = ((unsigned)ugl < (unsigned)HU_) ? a : 0.f;
        if (lr < 5) {
#pragma unroll
          for (int j = 0; j < 5; ++j) wv[j] = wv[j + 1];
          wv[5] = SD[(lr + 6) * 132 + c];
        }
      }
    } else {
#pragma unroll
      for (int j = 0; j < 6; ++j) wv[j] = SD[(6 + j) * 132 + c];
#pragma unroll
      for (int lr = 6; lr < 13; ++lr) {
        float a = fe[0]*wv[0] + fe[1]*wv[1] + fe[2]*wv[2] + fe[3]*wv[3] + fe[4]*wv[4] + fe[5]*wv[5];
        int ugl = 2 * y0 - 4 + 2 * lr;
        I1[(2 * lr + 1) * I1S + c] = ((unsigned)ugl < (unsigned)HU_) ? a : 0.f;
        if (lr < 12) {
#pragma unroll
          for (int j = 0; j < 5; ++j) wv[j] = wv[j + 1];
          wv[5] = SD[(lr + 6) * 132 + c];
        }
      }
#pragma unroll
      for (int j = 0; j < 6; ++j) wv[j] = SD[(7 + j) * 132 + c];
#pragma unroll
      for (int lr = 7; lr < 13; ++lr) {
        float a = fo[0]*wv[0] + fo[1]*wv[1] + fo[2]*wv[2] + fo[3]*wv[3] + fo[4]*wv[4] + fo[5]*wv[5];
        int ugl = 2 * y0 - 5 + 2 * lr;
        I1[(2 * lr) * I1S + c] = ((unsigned)ugl < (unsigned)HU_) ? a : 0.f;
        if (lr < 12) {
#pragma unroll
          for (int j = 0; j < 5; ++j) wv[j] = wv[j + 1];
          wv[5] = SD[(lr + 6) * 132 + c];
        }
      }
    }
    if (tid >= 200 && tid < 252) {
      int t2 = tid - 200;
      int c2 = 128 + (t2 & 1), u2 = t2 >> 1;
      float a = 0.f;
      if ((u2 & 1) == 0) {
        int lr = u2 >> 1;
#pragma unroll
        for (int j = 0; j < 6; ++j) a += fo[j] * SD[(lr + j) * 132 + c2];
      } else {
        int lr = (u2 - 1) >> 1;
#pragma unroll
        for (int j = 0; j < 6; ++j) a += fe[j] * SD[(lr + j) * 132 + c2];
      }
      int ugl = 2 * y0 - 5 + u2;
      I1[u2 * I1S + c2] = ((unsigned)ugl < (unsigned)HU_) ? a : 0.f;
    }
    if (tid < 52) {
      int r = tid >> 1, col = 130 + (tid & 1);
      I1[r * I1S + col] = 0.f;
    }
  }
  __syncthreads();

  for (int idx = tid; idx < 26 * 33; idx += 256) {
    int s = idx / 26, u = idx - 26 * s;
    const float* I1r = &I1[u * I1S];
    if (s < 32) {
      float w12[12];
      if (s == 0) {
        float4 qb = *(const float4*)&I1r[0];
        float4 qc = *(const float4*)&I1r[4];
        w12[0] = 0.f; w12[1] = 0.f; w12[2] = 0.f; w12[3] = 0.f;
        w12[4] = qb.x; w12[5] = qb.y; w12[6] = qb.z; w12[7] = qb.w;
        w12[8] = qc.x; w12[9] = qc.y; w12[10] = qc.z; w12[11] = qc.w;
      } else {
        int c0 = 4 * s;
        float4 qa = *(const float4*)&I1r[c0 - 4];
        float4 qb = *(const float4*)&I1r[c0];
        float4 qc = *(const float4*)&I1r[c0 + 4];
        w12[0] = qa.x; w12[1] = qa.y; w12[2] = qa.z; w12[3] = qa.w;
        w12[4] = qb.x; w12[5] = qb.y; w12[6] = qb.z; w12[7] = qb.w;
        w12[8] = qc.x; w12[9] = qc.y; w12[10] = qc.z; w12[11] = qc.w;
      }
      float o[8];
#pragma unroll
      for (int e = 0; e < 4; ++e) {
        o[2*e]   = fe[0]*w12[e+1] + fe[1]*w12[e+2] + fe[2]*w12[e+3] + fe[3]*w12[e+4] + fe[4]*w12[e+5] + fe[5]*w12[e+6];
        o[2*e+1] = fo[0]*w12[e+2] + fo[1]*w12[e+3] + fo[2]*w12[e+4] + fo[3]*w12[e+5] + fo[4]*w12[e+6] + fo[5]*w12[e+7];
      }
#pragma unroll
      for (int e = 0; e < 8; ++e) {
        float a = o[e];
        float m = (a >= 0.f) ? kPos : kNeg;
        a *= m;
        o[e] = fminf(fmaxf(a, -256.f), 256.f);
      }
      *(float4*)&I2[u * I2S + 8 * s]     = make_float4(o[0], o[1], o[2], o[3]);
      *(float4*)&I2[u * I2S + 8 * s + 4] = make_float4(o[4], o[5], o[6], o[7]);
    } else {
      float4 qa = *(const float4*)&I1r[124];
      float4 qb = *(const float4*)&I1r[128];
      float w8[8] = {qa.x, qa.y, qa.z, qa.w, qb.x, qb.y, qb.z, qb.w};
      float q[4];
      q[0] = fe[0]*w8[1] + fe[1]*w8[2] + fe[2]*w8[3] + fe[3]*w8[4] + fe[4]*w8[5] + fe[5]*w8[6];
      q[1] = fo[0]*w8[2] + fo[1]*w8[3] + fo[2]*w8[4] + fo[3]*w8[5] + fo[4]*w8[6] + fo[5]*w8[7];
      q[2] = fe[0]*w8[2] + fe[1]*w8[3] + fe[2]*w8[4] + fe[3]*w8[5] + fe[4]*w8[6] + fe[5]*w8[7];
      q[3] = fo[0]*w8[3] + fo[1]*w8[4] + fo[2]*w8[5] + fo[3]*w8[6] + fo[4]*w8[7];
      float q2[4];
#pragma unroll
      for (int e = 0; e < 4; ++e) {
        float a = q[e];
        float m = (a >= 0.f) ? kPos : kNeg;
        a *= m;
        q2[e] = fminf(fmaxf(a, -256.f), 256.f);
      }
      *(float4*)&I2[u * I2S + 256] = make_float4(q2[0], q2[1], q2[2], q2[3]);
    }
  }
  __syncthreads();

  {
    if (tid < 96) {
      int r = tid / 12, j = tid - 12 * r;
      int col = (j < 5) ? j : (260 + j);
      D[r * 272 + col] = 0.f;
    }
    auto p3col = [&](int v) {
      float wn[12];
#pragma unroll
      for (int t = 0; t < 12; ++t) wn[t] = I2[t * I2S + v];
#pragma unroll
      for (int y = 0; y < 8; ++y) {
        float a = 0.f;
#pragma unroll
        for (int t = 0; t < 12; ++t) a += fdt[t] * wn[t];
        D[y * 272 + v + 5] = a;
        if (y < 7) {
#pragma unroll
          for (int t = 0; t < 10; ++t) wn[t] = wn[t + 2];
          wn[10] = I2[(2 * y + 12) * I2S + v];
          wn[11] = I2[(2 * y + 13) * I2S + v];
        }
      }
    };
    p3col(tid);
    if (tid < 4) p3col(256 + tid);
  }
  __syncthreads();

  if (tid < 208) {
    int row = tid / 26, s4 = tid - 26 * row;
    int gy = y0 + row;
    if (gy < HO_) {
      float wn[20];
#pragma unroll
      for (int k = 0; k < 10; ++k) {
        float2 t2 = *(const float2*)&D[row * 272 + 10 * s4 + 2 * k];
        wn[2 * k] = t2.x;
        wn[2 * k + 1] = t2.y;
      }
      float* dp = dst + (size_t)plane * (HO_ * HO_) + gy * HO_ + 5 * s4;
#pragma unroll
      for (int q = 0; q < 5; ++q) {
        float a = 0.f;
#pragma unroll
        for (int t = 0; t < 12; ++t) a += fdt[t] * wn[2 * q + t];
        dp[q] = a;
      }
    }
  }
}

// ---------------- launch ----------------
extern "C" void kernel_launch(void* const* d_in, const int* in_sizes, int n_in,
                              void* d_out, int out_size, void* d_ws, size_t ws_size,
                              hipStream_t stream) {
  (void)in_sizes; (void)n_in; (void)out_size; (void)ws_size;
  const float* input  = (const float*)d_in[0];
  const float* style  = (const float*)d_in[1];
  const float* weight = (const float*)d_in[2];
  const float* mw     = (const float*)d_in[3];
  const float* mb     = (const float*)d_in[4];
  const float* bias   = (const float*)d_in[5];
  const float* upf    = (const float*)d_in[6];
  const float* dnf    = (const float*)d_in[7];
  float* out = (float*)d_out;

  float* out1   = (float*)d_ws;                               // 69.22 MB
  float* s      = out1 + (size_t)B_ * COUT_ * HO_ * HO_;      // [4][256]
  float* demod  = s + B_ * CIN_;                              // [4][256]
  ushort_t* Wth = (ushort_t*)(demod + B_ * COUT_);            // 1.18 MB
  float*    zp  = (float*)(Wth + 589824);                     // 16 B zero page
  ushort_t* Xt  = (ushort_t*)(zp + 4);                        // 32 MB (bf16)

  k_mod   <<<256, 256, 0, stream>>>(style, mw, mb, s);
  k_prep_x<<<dim3(256, 2, B_), 256, 0, stream>>>(input, s, Xt, zp);
  k_demod <<<256, 256, 0, stream>>>(weight, s, demod);
  k_prep_w<<<2304, 256, 0, stream>>>(weight, Wth);
  k_conv_mfma<<<dim3(9, 13, 8), 256, 0, stream>>>(Xt, Wth, demod, bias,
                                                  (const ushort_t*)zp, out1);
  k_fir   <<<dim3(17, 1024), 256, 0, stream>>>(out1, upf, dnf, out);
}

// Round 20
// 240.640 us; speedup vs baseline: 1.1030x; 1.1030x over previous
//
#include <hip/hip_runtime.h>
#include <hip/hip_bf16.h>
#include <math.h>

#define B_    4
#define CIN_  256
#define COUT_ 256
#define H_    128
#define W_    128
#define HW_   16384
#define SD_   512
#define HO_   130
#define HU_   260
#define NT_   12

typedef unsigned short ushort_t;
typedef __attribute__((ext_vector_type(8))) short short8;
typedef __attribute__((ext_vector_type(4))) float f32x4;

__device__ inline ushort_t f2bf_(float v) {
  union { float f; unsigned u; } x; x.f = v;
  unsigned r = x.u + 0x7fffu + ((x.u >> 16) & 1u);
  return (ushort_t)(r >> 16);
}
__device__ inline void gll16(const ushort_t* g, ushort_t* l) {
  __builtin_amdgcn_global_load_lds(
      (const __attribute__((address_space(1))) unsigned int*)g,
      (__attribute__((address_space(3))) unsigned int*)l, 16, 0, 0);
}

// ---------------- K1: modulation s[b][cin] ----------------
__global__ __launch_bounds__(256) void k_mod(const float* __restrict__ style,
                                             const float* __restrict__ mw,
                                             const float* __restrict__ mb,
                                             float* __restrict__ s) {
  int wid  = (blockIdx.x * blockDim.x + threadIdx.x) >> 6;
  int lane = threadIdx.x & 63;
  int b = wid >> 8, ci = wid & 255;
  const float* st = style + b * SD_;
  const float* w  = mw + ci * SD_;
  float acc = 0.f;
  for (int k = lane; k < SD_; k += 64) acc += st[k] * w[k];
  for (int off = 32; off; off >>= 1) acc += __shfl_down(acc, off);
  if (lane == 0) s[wid] = acc * 0.044194173824159216f + mb[ci];
}

// ---------------- K2: demod[b][cout] ----------------
__global__ __launch_bounds__(256) void k_demod(const float* __restrict__ weight,
                                               const float* __restrict__ s,
                                               float* __restrict__ demod) {
  int wid  = (blockIdx.x * blockDim.x + threadIdx.x) >> 6;
  int lane = threadIdx.x & 63;
  int b = wid >> 8, co = wid & 255;
  const float* wrow = weight + co * CIN_ * 9;
  const float* sb   = s + b * CIN_;
  float acc = 0.f;
  for (int e = lane; e < CIN_ * 9; e += 64) {
    float p = wrow[e] * sb[e / 9];
    acc += p * p;
  }
  for (int off = 32; off; off >>= 1) acc += __shfl_down(acc, off);
  if (lane == 0) demod[wid] = rsqrtf(acc + 1e-8f);
}

// ---------------- K2b: weight pre-transform (bf16) ----------------
__global__ __launch_bounds__(256) void k_prep_w(const float* __restrict__ W,
                                                ushort_t* __restrict__ Wth) {
  int idx = blockIdx.x * 256 + threadIdx.x;
  if (idx >= 589824) return;
  int j  = idx & 7;
  int co = (idx >> 3) & 127;
  int kc = (idx >> 10) & 3;
  int kb = (idx >> 12) & 7;
  int cb = (idx >> 15) & 1;
  int t  = idx >> 16;
  int ci  = kb * 32 + kc * 8 + j;
  int cog = cb * 128 + co;
  Wth[idx] = f2bf_(W[(cog * CIN_ + ci) * 9 + t]);
}

// ---------------- K2c: X pre-transform (pure bf16) ----------------
__global__ __launch_bounds__(256) void k_prep_x(const float* __restrict__ input,
                                                const float* __restrict__ s,
                                                ushort_t* __restrict__ Xt,
                                                float* __restrict__ zp) {
  int b = blockIdx.z, cb = blockIdx.y, px0 = blockIdx.x * 64;
  int tid = threadIdx.x;
  __shared__ float T[64 * 131];
  __shared__ float sSh[128];
  if (tid < 128) sSh[tid] = s[b * 256 + cb * 128 + tid];
  if (blockIdx.x == 0 && blockIdx.y == 0 && blockIdx.z == 0 && tid < 4)
    zp[tid] = 0.f;
  __syncthreads();
  const float* inb = input + (size_t)(b * 256 + cb * 128) * HW_ + px0;
#pragma unroll
  for (int r2 = 0; r2 < 32; ++r2) {
    int idx = r2 * 256 + tid;
    int ci = idx >> 6, p = idx & 63;
    T[p * 131 + ci] = inb[(size_t)ci * HW_ + p] * sSh[ci];
  }
  __syncthreads();
  ushort_t* xb = Xt + (size_t)b * HW_ * 256 + cb * 128;
#pragma unroll
  for (int r2 = 0; r2 < 16; ++r2) {
    int u = r2 * 256 + tid;
    int cp = u & 63, p = u >> 6;
    float v0 = T[p * 131 + 2 * cp], v1 = T[p * 131 + 2 * cp + 1];
    unsigned pk = (unsigned)f2bf_(v0) | ((unsigned)f2bf_(v1) << 16);
    *(unsigned*)(xb + ((size_t)(px0 + p)) * 256 + cp * 2) = pk;
  }
}

// ---------------- K3: modulated conv via MFMA (X bf16, W bf16; 3 blocks/CU) ----------------
#define XCELLS 864
#define XROUNDS 4
#define XBUFU  1024

__global__ __launch_bounds__(256, 3) void k_conv_mfma(
    const ushort_t* __restrict__ Xt, const ushort_t* __restrict__ Wth,
    const float* __restrict__ demod, const float* __restrict__ bias,
    const ushort_t* __restrict__ zpg, float* __restrict__ out1) {
  const int tid = threadIdx.x;
  const int b = blockIdx.z >> 1, cb = blockIdx.z & 1;
  const int y0 = blockIdx.y * 10, x0 = blockIdx.x * 16;
  const int lane = tid & 63, lr = lane & 15, kcc = lane >> 4;
  const int w = tid >> 6;

  __shared__ __align__(16) ushort_t XL[2][XBUFU * 8];

  f32x4 acc[2][10];
#pragma unroll
  for (int i = 0; i < 2; ++i)
#pragma unroll
    for (int jj = 0; jj < 10; ++jj) acc[i][jj] = (f32x4)0.f;

  const ushort_t* gsrc[XROUNDS];
  bool okr[XROUNDS];
#pragma unroll
  for (int r = 0; r < XROUNDS; ++r) {
    int u = r * 256 + tid;
    const ushort_t* p = zpg;
    bool ok = false;
    if (u < XCELLS) {
      int kc = u / 216, cell = u - kc * 216;
      int hy = cell / 18, hx = cell - hy * 18;
      int iy = y0 + hy - 2, ix = x0 + hx - 2;
      if ((unsigned)iy < 128u && (unsigned)ix < 128u) {
        p = Xt + (((size_t)b * HW_ + iy * W_ + ix) << 8) + kc * 8;
        ok = true;
      }
    }
    gsrc[r] = p; okr[r] = ok;
  }

  auto stage = [&](int kb, int bufsel) {
    ushort_t* lb = &XL[bufsel][(size_t)tid * 8];
#pragma unroll
    for (int r = 0; r < XROUNDS; ++r) {
      const ushort_t* g = okr[r] ? gsrc[r] + kb * 32 : zpg;
      gll16(g, lb + r * 2048);
    }
  };

  stage(0, 0);
  __syncthreads();

  for (int kb = 0; kb < 8; ++kb) {
    const ushort_t* Xc = &XL[kb & 1][0];
    const int wbo = cb * 32768 + kb * 4096 + kcc * 1024 + (w * 32 + lr) * 8;
#pragma unroll
    for (int kx = 0; kx < 3; ++kx) {
      short8 ah[3][2];
#pragma unroll
      for (int ky = 0; ky < 3; ++ky) {
        const ushort_t* wh = Wth + wbo + (ky * 3 + kx) * 65536;
        ah[ky][0] = *(const short8*)wh;
        ah[ky][1] = *(const short8*)(wh + 128);
      }
      if (kx == 0) {
        __builtin_amdgcn_sched_barrier(0);
        if (kb < 7) stage(kb + 1, (kb & 1) ^ 1);
      }
#pragma unroll
      for (int r = 0; r < 12; ++r) {
        const int c16 = (kcc * 216 + r * 18 + lr + kx) * 8;
        short8 bh = *(const short8*)&Xc[c16];
#pragma unroll
        for (int ky = 0; ky < 3; ++ky) {
          const int bn = r - ky;
          if (bn >= 0 && bn < 10) {
            acc[0][bn] = __builtin_amdgcn_mfma_f32_16x16x32_bf16(ah[ky][0], bh, acc[0][bn], 0, 0, 0);
            acc[1][bn] = __builtin_amdgcn_mfma_f32_16x16x32_bf16(ah[ky][1], bh, acc[1][bn], 0, 0, 0);
          }
        }
      }
    }
    if (kb < 7) __syncthreads();
  }

#pragma unroll
  for (int am = 0; am < 2; ++am) {
#pragma unroll
    for (int r = 0; r < 4; ++r) {
      int cog = cb * 128 + w * 32 + am * 16 + kcc * 4 + r;
      float dm = demod[b * 256 + cog];
      float bv = bias[cog];
      int ox = x0 + lr;
      if (ox < HO_) {
#pragma unroll
        for (int bn = 0; bn < 10; ++bn) {
          int oy = y0 + bn;
          out1[((b * 256 + cog) * HO_ + oy) * HO_ + ox] = acc[am][bn][r] * dm + bv;
        }
      }
    }
  }
}

// ---------------- K4: fused FIR (R20: P1 register row-window, P3 full-column regs) ----------------
#define I1S 132
#define I2S 260

__global__ __launch_bounds__(256) void k_fir(const float* __restrict__ src,
                                             const float* __restrict__ upf,
                                             const float* __restrict__ dnf,
                                             float* __restrict__ dst) {
  const int plane = blockIdx.y;
  const int y0 = blockIdx.x * 8;
  const int tid = threadIdx.x;

  __shared__ __align__(16) float I1D[26 * I1S];   // I1 (P1->P2), then D 8x272 (P3->P4)
  __shared__ __align__(16) float B2[26 * I2S];    // SD 18x132 (P0->P1), then I2 (P2->P3)

  float* SD = B2;
  float* I2 = B2;
  float* I1 = I1D;
  float* D  = I1D;

  float fe[6], fo[6], fdt[12];
#pragma unroll
  for (int j = 0; j < 6; ++j) { fe[j] = upf[2 * j] * 2.f; fo[j] = upf[2 * j + 1] * 2.f; }
#pragma unroll
  for (int t = 0; t < NT_; ++t) fdt[t] = dnf[t];
  const float kPos = 1.41421356237309515f, kNeg = 0.28284271247461903f;

  // ---- P0: stage src rows [y0-5, y0+13) as float4 LDS writes ----
  const float* sp = src + (size_t)plane * (HO_ * HO_);
#pragma unroll
  for (int k = 0; k < 3; ++k) {
    int idx = tid + k * 256;
    if (idx < 594) {
      int r = idx / 33, q = idx - 33 * r;
      int gy = y0 - 5 + r;
      int cbase = 4 * q;
      float4 v = make_float4(0.f, 0.f, 0.f, 0.f);
      if ((unsigned)gy < (unsigned)HO_) {
        const float* rp = sp + gy * HO_ + cbase;
        v.x = rp[0];
        v.y = (cbase + 1 < HO_) ? rp[1] : 0.f;
        v.z = (cbase + 2 < HO_) ? rp[2] : 0.f;
        v.w = (cbase + 3 < HO_) ? rp[3] : 0.f;
      }
      *(float4*)&SD[r * 132 + cbase] = v;
    }
  }
  __syncthreads();

  // ---- P1: vertical up-FIR -> I1[u][c], 12-row register window per half ----
  {
    int c = tid & 127, uh = tid >> 7;
    int base = uh ? 6 : 0;
    float rw[12];
#pragma unroll
    for (int j = 0; j < 12; ++j) rw[j] = SD[(base + j) * 132 + c];
    if (uh == 0) {
      // evens u=2lr (taps fo), lr 0..6, rows lr..lr+5
#pragma unroll
      for (int lr = 0; lr < 7; ++lr) {
        float a = fo[0]*rw[lr] + fo[1]*rw[lr+1] + fo[2]*rw[lr+2] + fo[3]*rw[lr+3] + fo[4]*rw[lr+4] + fo[5]*rw[lr+5];
        int ugl = 2 * y0 - 5 + 2 * lr;
        I1[(2 * lr) * I1S + c] = ((unsigned)ugl < (unsigned)HU_) ? a : 0.f;
      }
      // odds u=2lr+1 (taps fe), lr 0..5, rows lr..lr+5
#pragma unroll
      for (int lr = 0; lr < 6; ++lr) {
        float a = fe[0]*rw[lr] + fe[1]*rw[lr+1] + fe[2]*rw[lr+2] + fe[3]*rw[lr+3] + fe[4]*rw[lr+4] + fe[5]*rw[lr+5];
        int ugl = 2 * y0 - 4 + 2 * lr;
        I1[(2 * lr + 1) * I1S + c] = ((unsigned)ugl < (unsigned)HU_) ? a : 0.f;
      }
    } else {
      // odds u=2lr+1 (taps fe), lr 6..12, rows lr..lr+5 = rw[lr-6..lr-1]
#pragma unroll
      for (int lr = 6; lr < 13; ++lr) {
        float a = fe[0]*rw[lr-6] + fe[1]*rw[lr-5] + fe[2]*rw[lr-4] + fe[3]*rw[lr-3] + fe[4]*rw[lr-2] + fe[5]*rw[lr-1];
        int ugl = 2 * y0 - 4 + 2 * lr;
        I1[(2 * lr + 1) * I1S + c] = ((unsigned)ugl < (unsigned)HU_) ? a : 0.f;
      }
      // evens u=2lr (taps fo), lr 7..12, rows lr..lr+5 = rw[lr-6..lr-1]
#pragma unroll
      for (int lr = 7; lr < 13; ++lr) {
        float a = fo[0]*rw[lr-6] + fo[1]*rw[lr-5] + fo[2]*rw[lr-4] + fo[3]*rw[lr-3] + fo[4]*rw[lr-2] + fo[5]*rw[lr-1];
        int ugl = 2 * y0 - 5 + 2 * lr;
        I1[(2 * lr) * I1S + c] = ((unsigned)ugl < (unsigned)HU_) ? a : 0.f;
      }
    }
    if (tid >= 200 && tid < 252) {
      int t2 = tid - 200;
      int c2 = 128 + (t2 & 1), u2 = t2 >> 1;
      float a = 0.f;
      if ((u2 & 1) == 0) {
        int lr = u2 >> 1;
#pragma unroll
        for (int j = 0; j < 6; ++j) a += fo[j] * SD[(lr + j) * 132 + c2];
      } else {
        int lr = (u2 - 1) >> 1;
#pragma unroll
        for (int j = 0; j < 6; ++j) a += fe[j] * SD[(lr + j) * 132 + c2];
      }
      int ugl = 2 * y0 - 5 + u2;
      I1[u2 * I1S + c2] = ((unsigned)ugl < (unsigned)HU_) ? a : 0.f;
    }
    if (tid < 52) {
      int r = tid >> 1, col = 130 + (tid & 1);
      I1[r * I1S + col] = 0.f;
    }
  }
  __syncthreads();

  // ---- P2: horizontal up-FIR + lrelu + clamp -> I2[u][v] (aligned float4 window) ----
  for (int idx = tid; idx < 26 * 33; idx += 256) {
    int s = idx / 26, u = idx - 26 * s;
    const float* I1r = &I1[u * I1S];
    if (s < 32) {
      float w12[12];
      if (s == 0) {
        float4 qb = *(const float4*)&I1r[0];
        float4 qc = *(const float4*)&I1r[4];
        w12[0] = 0.f; w12[1] = 0.f; w12[2] = 0.f; w12[3] = 0.f;
        w12[4] = qb.x; w12[5] = qb.y; w12[6] = qb.z; w12[7] = qb.w;
        w12[8] = qc.x; w12[9] = qc.y; w12[10] = qc.z; w12[11] = qc.w;
      } else {
        int c0 = 4 * s;
        float4 qa = *(const float4*)&I1r[c0 - 4];
        float4 qb = *(const float4*)&I1r[c0];
        float4 qc = *(const float4*)&I1r[c0 + 4];
        w12[0] = qa.x; w12[1] = qa.y; w12[2] = qa.z; w12[3] = qa.w;
        w12[4] = qb.x; w12[5] = qb.y; w12[6] = qb.z; w12[7] = qb.w;
        w12[8] = qc.x; w12[9] = qc.y; w12[10] = qc.z; w12[11] = qc.w;
      }
      float o[8];
#pragma unroll
      for (int e = 0; e < 4; ++e) {
        o[2*e]   = fe[0]*w12[e+1] + fe[1]*w12[e+2] + fe[2]*w12[e+3] + fe[3]*w12[e+4] + fe[4]*w12[e+5] + fe[5]*w12[e+6];
        o[2*e+1] = fo[0]*w12[e+2] + fo[1]*w12[e+3] + fo[2]*w12[e+4] + fo[3]*w12[e+5] + fo[4]*w12[e+6] + fo[5]*w12[e+7];
      }
#pragma unroll
      for (int e = 0; e < 8; ++e) {
        float a = o[e];
        float m = (a >= 0.f) ? kPos : kNeg;
        a *= m;
        o[e] = fminf(fmaxf(a, -256.f), 256.f);
      }
      *(float4*)&I2[u * I2S + 8 * s]     = make_float4(o[0], o[1], o[2], o[3]);
      *(float4*)&I2[u * I2S + 8 * s + 4] = make_float4(o[4], o[5], o[6], o[7]);
    } else {
      float4 qa = *(const float4*)&I1r[124];
      float4 qb = *(const float4*)&I1r[128];
      float w8[8] = {qa.x, qa.y, qa.z, qa.w, qb.x, qb.y, qb.z, qb.w};
      float q[4];
      q[0] = fe[0]*w8[1] + fe[1]*w8[2] + fe[2]*w8[3] + fe[3]*w8[4] + fe[4]*w8[5] + fe[5]*w8[6];
      q[1] = fo[0]*w8[2] + fo[1]*w8[3] + fo[2]*w8[4] + fo[3]*w8[5] + fo[4]*w8[6] + fo[5]*w8[7];
      q[2] = fe[0]*w8[2] + fe[1]*w8[3] + fe[2]*w8[4] + fe[3]*w8[5] + fe[4]*w8[6] + fe[5]*w8[7];
      q[3] = fo[0]*w8[3] + fo[1]*w8[4] + fo[2]*w8[5] + fo[3]*w8[6] + fo[4]*w8[7];
      float q2[4];
#pragma unroll
      for (int e = 0; e < 4; ++e) {
        float a = q[e];
        float m = (a >= 0.f) ? kPos : kNeg;
        a *= m;
        q2[e] = fminf(fmaxf(a, -256.f), 256.f);
      }
      *(float4*)&I2[u * I2S + 256] = make_float4(q2[0], q2[1], q2[2], q2[3]);
    }
  }
  __syncthreads();

  // ---- P3: vertical down-FIR -> D[y][v+5], full 26-row register column ----
  {
    if (tid < 96) {
      int r = tid / 12, j = tid - 12 * r;
      int col = (j < 5) ? j : (260 + j);
      D[r * 272 + col] = 0.f;
    }
    auto p3col = [&](int v) {
      float wn[26];
#pragma unroll
      for (int t = 0; t < 26; ++t) wn[t] = I2[t * I2S + v];
#pragma unroll
      for (int y = 0; y < 8; ++y) {
        float a = 0.f;
#pragma unroll
        for (int t = 0; t < 12; ++t) a += fdt[t] * wn[2 * y + t];
        D[y * 272 + v + 5] = a;
      }
    };
    p3col(tid);
    if (tid < 4) p3col(256 + tid);
  }
  __syncthreads();

  // ---- P4: horizontal down-FIR -> global (float2 LDS reads) ----
  if (tid < 208) {
    int row = tid / 26, s4 = tid - 26 * row;
    int gy = y0 + row;
    if (gy < HO_) {
      float wn[20];
#pragma unroll
      for (int k = 0; k < 10; ++k) {
        float2 t2 = *(const float2*)&D[row * 272 + 10 * s4 + 2 * k];
        wn[2 * k] = t2.x;
        wn[2 * k + 1] = t2.y;
      }
      float* dp = dst + (size_t)plane * (HO_ * HO_) + gy * HO_ + 5 * s4;
#pragma unroll
      for (int q = 0; q < 5; ++q) {
        float a = 0.f;
#pragma unroll
        for (int t = 0; t < 12; ++t) a += fdt[t] * wn[2 * q + t];
        dp[q] = a;
      }
    }
  }
}

// ---------------- launch ----------------
extern "C" void kernel_launch(void* const* d_in, const int* in_sizes, int n_in,
                              void* d_out, int out_size, void* d_ws, size_t ws_size,
                              hipStream_t stream) {
  (void)in_sizes; (void)n_in; (void)out_size; (void)ws_size;
  const float* input  = (const float*)d_in[0];
  const float* style  = (const float*)d_in[1];
  const float* weight = (const float*)d_in[2];
  const float* mw     = (const float*)d_in[3];
  const float* mb     = (const float*)d_in[4];
  const float* bias   = (const float*)d_in[5];
  const float* upf    = (const float*)d_in[6];
  const float* dnf    = (const float*)d_in[7];
  float* out = (float*)d_out;

  float* out1   = (float*)d_ws;                               // 69.22 MB
  float* s      = out1 + (size_t)B_ * COUT_ * HO_ * HO_;      // [4][256]
  float* demod  = s + B_ * CIN_;                              // [4][256]
  ushort_t* Wth = (ushort_t*)(demod + B_ * COUT_);            // 1.18 MB
  float*    zp  = (float*)(Wth + 589824);                     // 16 B zero page
  ushort_t* Xt  = (ushort_t*)(zp + 4);                        // 32 MB (bf16)

  k_mod   <<<256, 256, 0, stream>>>(style, mw, mb, s);
  k_prep_x<<<dim3(256, 2, B_), 256, 0, stream>>>(input, s, Xt, zp);
  k_demod <<<256, 256, 0, stream>>>(weight, s, demod);
  k_prep_w<<<2304, 256, 0, stream>>>(weight, Wth);
  k_conv_mfma<<<dim3(9, 13, 8), 256, 0, stream>>>(Xt, Wth, demod, bias,
                                                  (const ushort_t*)zp, out1);
  k_fir   <<<dim3(17, 1024), 256, 0, stream>>>(out1, upf, dnf, out);
}

// Round 21
// 224.833 us; speedup vs baseline: 1.1805x; 1.0703x over previous
//
#include <hip/hip_runtime.h>
#include <hip/hip_bf16.h>
#include <math.h>

#define B_    4
#define CIN_  256
#define COUT_ 256
#define H_    128
#define W_    128
#define HW_   16384
#define SD_   512
#define HO_   130
#define HU_   260
#define NT_   12

typedef unsigned short ushort_t;
typedef __attribute__((ext_vector_type(8))) short short8;
typedef __attribute__((ext_vector_type(4))) float f32x4;
typedef __attribute__((ext_vector_type(2))) float f32x2;

__device__ inline ushort_t f2bf_(float v) {
  union { float f; unsigned u; } x; x.f = v;
  unsigned r = x.u + 0x7fffu + ((x.u >> 16) & 1u);
  return (ushort_t)(r >> 16);
}
__device__ inline void gll16(const ushort_t* g, ushort_t* l) {
  __builtin_amdgcn_global_load_lds(
      (const __attribute__((address_space(1))) unsigned int*)g,
      (__attribute__((address_space(3))) unsigned int*)l, 16, 0, 0);
}

// ---------------- K1: modulation s[b][cin] ----------------
__global__ __launch_bounds__(256) void k_mod(const float* __restrict__ style,
                                             const float* __restrict__ mw,
                                             const float* __restrict__ mb,
                                             float* __restrict__ s) {
  int wid  = (blockIdx.x * blockDim.x + threadIdx.x) >> 6;
  int lane = threadIdx.x & 63;
  int b = wid >> 8, ci = wid & 255;
  const float* st = style + b * SD_;
  const float* w  = mw + ci * SD_;
  float acc = 0.f;
  for (int k = lane; k < SD_; k += 64) acc += st[k] * w[k];
  for (int off = 32; off; off >>= 1) acc += __shfl_down(acc, off);
  if (lane == 0) s[wid] = acc * 0.044194173824159216f + mb[ci];
}

// ---------------- K2: demod[b][cout] ----------------
__global__ __launch_bounds__(256) void k_demod(const float* __restrict__ weight,
                                               const float* __restrict__ s,
                                               float* __restrict__ demod) {
  int wid  = (blockIdx.x * blockDim.x + threadIdx.x) >> 6;
  int lane = threadIdx.x & 63;
  int b = wid >> 8, co = wid & 255;
  const float* wrow = weight + co * CIN_ * 9;
  const float* sb   = s + b * CIN_;
  float acc = 0.f;
  for (int e = lane; e < CIN_ * 9; e += 64) {
    float p = wrow[e] * sb[e / 9];
    acc += p * p;
  }
  for (int off = 32; off; off >>= 1) acc += __shfl_down(acc, off);
  if (lane == 0) demod[wid] = rsqrtf(acc + 1e-8f);
}

// ---------------- K2b: weight pre-transform (bf16) ----------------
__global__ __launch_bounds__(256) void k_prep_w(const float* __restrict__ W,
                                                ushort_t* __restrict__ Wth) {
  int idx = blockIdx.x * 256 + threadIdx.x;
  if (idx >= 589824) return;
  int j  = idx & 7;
  int co = (idx >> 3) & 127;
  int kc = (idx >> 10) & 3;
  int kb = (idx >> 12) & 7;
  int cb = (idx >> 15) & 1;
  int t  = idx >> 16;
  int ci  = kb * 32 + kc * 8 + j;
  int cog = cb * 128 + co;
  Wth[idx] = f2bf_(W[(cog * CIN_ + ci) * 9 + t]);
}

// ---------------- K2c: X pre-transform (pure bf16) ----------------
__global__ __launch_bounds__(256) void k_prep_x(const float* __restrict__ input,
                                                const float* __restrict__ s,
                                                ushort_t* __restrict__ Xt,
                                                float* __restrict__ zp) {
  int b = blockIdx.z, cb = blockIdx.y, px0 = blockIdx.x * 64;
  int tid = threadIdx.x;
  __shared__ float T[64 * 131];
  __shared__ float sSh[128];
  if (tid < 128) sSh[tid] = s[b * 256 + cb * 128 + tid];
  if (blockIdx.x == 0 && blockIdx.y == 0 && blockIdx.z == 0 && tid < 4)
    zp[tid] = 0.f;
  __syncthreads();
  const float* inb = input + (size_t)(b * 256 + cb * 128) * HW_ + px0;
#pragma unroll
  for (int r2 = 0; r2 < 32; ++r2) {
    int idx = r2 * 256 + tid;
    int ci = idx >> 6, p = idx & 63;
    T[p * 131 + ci] = inb[(size_t)ci * HW_ + p] * sSh[ci];
  }
  __syncthreads();
  ushort_t* xb = Xt + (size_t)b * HW_ * 256 + cb * 128;
#pragma unroll
  for (int r2 = 0; r2 < 16; ++r2) {
    int u = r2 * 256 + tid;
    int cp = u & 63, p = u >> 6;
    float v0 = T[p * 131 + 2 * cp], v1 = T[p * 131 + 2 * cp + 1];
    unsigned pk = (unsigned)f2bf_(v0) | ((unsigned)f2bf_(v1) << 16);
    *(unsigned*)(xb + ((size_t)(px0 + p)) * 256 + cp * 2) = pk;
  }
}

// ---------------- K3: modulated conv via MFMA (X bf16, W bf16; 3 blocks/CU) ----------------
#define XCELLS 864
#define XROUNDS 4
#define XBUFU  1024

__global__ __launch_bounds__(256, 3) void k_conv_mfma(
    const ushort_t* __restrict__ Xt, const ushort_t* __restrict__ Wth,
    const float* __restrict__ demod, const float* __restrict__ bias,
    const ushort_t* __restrict__ zpg, float* __restrict__ out1) {
  const int tid = threadIdx.x;
  const int b = blockIdx.z >> 1, cb = blockIdx.z & 1;
  const int y0 = blockIdx.y * 10, x0 = blockIdx.x * 16;
  const int lane = tid & 63, lr = lane & 15, kcc = lane >> 4;
  const int w = tid >> 6;

  __shared__ __align__(16) ushort_t XL[2][XBUFU * 8];

  f32x4 acc[2][10];
#pragma unroll
  for (int i = 0; i < 2; ++i)
#pragma unroll
    for (int jj = 0; jj < 10; ++jj) acc[i][jj] = (f32x4)0.f;

  const ushort_t* gsrc[XROUNDS];
  bool okr[XROUNDS];
#pragma unroll
  for (int r = 0; r < XROUNDS; ++r) {
    int u = r * 256 + tid;
    const ushort_t* p = zpg;
    bool ok = false;
    if (u < XCELLS) {
      int kc = u / 216, cell = u - kc * 216;
      int hy = cell / 18, hx = cell - hy * 18;
      int iy = y0 + hy - 2, ix = x0 + hx - 2;
      if ((unsigned)iy < 128u && (unsigned)ix < 128u) {
        p = Xt + (((size_t)b * HW_ + iy * W_ + ix) << 8) + kc * 8;
        ok = true;
      }
    }
    gsrc[r] = p; okr[r] = ok;
  }

  auto stage = [&](int kb, int bufsel) {
    ushort_t* lb = &XL[bufsel][(size_t)tid * 8];
#pragma unroll
    for (int r = 0; r < XROUNDS; ++r) {
      const ushort_t* g = okr[r] ? gsrc[r] + kb * 32 : zpg;
      gll16(g, lb + r * 2048);
    }
  };

  stage(0, 0);
  __syncthreads();

  for (int kb = 0; kb < 8; ++kb) {
    const ushort_t* Xc = &XL[kb & 1][0];
    const int wbo = cb * 32768 + kb * 4096 + kcc * 1024 + (w * 32 + lr) * 8;
#pragma unroll
    for (int kx = 0; kx < 3; ++kx) {
      short8 ah[3][2];
#pragma unroll
      for (int ky = 0; ky < 3; ++ky) {
        const ushort_t* wh = Wth + wbo + (ky * 3 + kx) * 65536;
        ah[ky][0] = *(const short8*)wh;
        ah[ky][1] = *(const short8*)(wh + 128);
      }
      if (kx == 0) {
        __builtin_amdgcn_sched_barrier(0);
        if (kb < 7) stage(kb + 1, (kb & 1) ^ 1);
      }
#pragma unroll
      for (int r = 0; r < 12; ++r) {
        const int c16 = (kcc * 216 + r * 18 + lr + kx) * 8;
        short8 bh = *(const short8*)&Xc[c16];
#pragma unroll
        for (int ky = 0; ky < 3; ++ky) {
          const int bn = r - ky;
          if (bn >= 0 && bn < 10) {
            acc[0][bn] = __builtin_amdgcn_mfma_f32_16x16x32_bf16(ah[ky][0], bh, acc[0][bn], 0, 0, 0);
            acc[1][bn] = __builtin_amdgcn_mfma_f32_16x16x32_bf16(ah[ky][1], bh, acc[1][bn], 0, 0, 0);
          }
        }
      }
    }
    if (kb < 7) __syncthreads();
  }

#pragma unroll
  for (int am = 0; am < 2; ++am) {
#pragma unroll
    for (int r = 0; r < 4; ++r) {
      int cog = cb * 128 + w * 32 + am * 16 + kcc * 4 + r;
      float dm = demod[b * 256 + cog];
      float bv = bias[cog];
      int ox = x0 + lr;
      if (ox < HO_) {
#pragma unroll
        for (int bn = 0; bn < 10; ++bn) {
          int oy = y0 + bn;
          out1[((b * 256 + cog) * HO_ + oy) * HO_ + ox] = acc[am][bn][r] * dm + bv;
        }
      }
    }
  }
}

// ---------------- K4: fused FIR (R21: packed-pair fp32 within one plane) ----------------
#define I1S 132
#define I2S 260

__global__ __launch_bounds__(256) void k_fir(const float* __restrict__ src,
                                             const float* __restrict__ upf,
                                             const float* __restrict__ dnf,
                                             float* __restrict__ dst) {
  const int plane = blockIdx.y;
  const int y0 = blockIdx.x * 8;
  const int tid = threadIdx.x;

  __shared__ __align__(16) float I1D[26 * I1S];   // I1 (P1->P2), then D 8x272 (P3->P4)
  __shared__ __align__(16) float B2[26 * I2S];    // SD 18x132 (P0->P1), then I2 (P2->P3)

  float* SD = B2;
  float* I2 = B2;
  float* I1 = I1D;
  float* D  = I1D;

  float fe[6], fo[6], fdt[12];
#pragma unroll
  for (int j = 0; j < 6; ++j) { fe[j] = upf[2 * j] * 2.f; fo[j] = upf[2 * j + 1] * 2.f; }
#pragma unroll
  for (int t = 0; t < NT_; ++t) fdt[t] = dnf[t];
  const float kPos = 1.41421356237309515f, kNeg = 0.28284271247461903f;

  // ---- P0: stage src rows [y0-5, y0+13) as float4 LDS writes ----
  const float* sp = src + (size_t)plane * (HO_ * HO_);
#pragma unroll
  for (int k = 0; k < 3; ++k) {
    int idx = tid + k * 256;
    if (idx < 594) {
      int r = idx / 33, q = idx - 33 * r;
      int gy = y0 - 5 + r;
      int cbase = 4 * q;
      float4 v = make_float4(0.f, 0.f, 0.f, 0.f);
      if ((unsigned)gy < (unsigned)HO_) {
        const float* rp = sp + gy * HO_ + cbase;
        v.x = rp[0];
        v.y = (cbase + 1 < HO_) ? rp[1] : 0.f;
        v.z = (cbase + 2 < HO_) ? rp[2] : 0.f;
        v.w = (cbase + 3 < HO_) ? rp[3] : 0.f;
      }
      *(float4*)&SD[r * 132 + cbase] = v;
    }
  }
  __syncthreads();

  // ---- P1: vertical up-FIR -> I1[u][c], packed pairs (u=2p even:fo, u=2p+1 odd:fe)
  //      both halves of a pair share window rows p..p+5 ----
  {
    int c = tid & 127, uh = tid >> 7;
    int base = uh ? 6 : 0;
    float rw[12];
#pragma unroll
    for (int j = 0; j < 12; ++j) rw[j] = SD[(base + j) * 132 + c];
    f32x2 fp2[6];
#pragma unroll
    for (int j = 0; j < 6; ++j) fp2[j] = (f32x2){fo[j], fe[j]};
    if (uh == 0) {
#pragma unroll
      for (int p = 0; p < 7; ++p) {        // pairs p=0..6 (u=0..13)
        f32x2 a = (f32x2)0.f;
#pragma unroll
        for (int j = 0; j < 6; ++j) a += fp2[j] * rw[p + j];
        int ug0 = 2 * y0 - 5 + 2 * p;
        int ug1 = 2 * y0 - 4 + 2 * p;
        I1[(2 * p) * I1S + c]     = ((unsigned)ug0 < (unsigned)HU_) ? a.x : 0.f;
        I1[(2 * p + 1) * I1S + c] = ((unsigned)ug1 < (unsigned)HU_) ? a.y : 0.f;
      }
    } else {
#pragma unroll
      for (int p = 7; p < 13; ++p) {       // pairs p=7..12 (u=14..25), rows p..p+5 = rw[p-6..p-1]
        f32x2 a = (f32x2)0.f;
#pragma unroll
        for (int j = 0; j < 6; ++j) a += fp2[j] * rw[p - 6 + j];
        int ug0 = 2 * y0 - 5 + 2 * p;
        int ug1 = 2 * y0 - 4 + 2 * p;
        I1[(2 * p) * I1S + c]     = ((unsigned)ug0 < (unsigned)HU_) ? a.x : 0.f;
        I1[(2 * p + 1) * I1S + c] = ((unsigned)ug1 < (unsigned)HU_) ? a.y : 0.f;
      }
    }
    if (tid >= 200 && tid < 252) {
      int t2 = tid - 200;
      int c2 = 128 + (t2 & 1), u2 = t2 >> 1;
      float a = 0.f;
      if ((u2 & 1) == 0) {
        int lr = u2 >> 1;
#pragma unroll
        for (int j = 0; j < 6; ++j) a += fo[j] * SD[(lr + j) * 132 + c2];
      } else {
        int lr = (u2 - 1) >> 1;
#pragma unroll
        for (int j = 0; j < 6; ++j) a += fe[j] * SD[(lr + j) * 132 + c2];
      }
      int ugl = 2 * y0 - 5 + u2;
      I1[u2 * I1S + c2] = ((unsigned)ugl < (unsigned)HU_) ? a : 0.f;
    }
    if (tid < 52) {
      int r = tid >> 1, col = 130 + (tid & 1);
      I1[r * I1S + col] = 0.f;
    }
  }
  __syncthreads();

  // ---- P2: horizontal up-FIR + lrelu + clamp -> I2[u][v]
  //      packed: {o[2e],o[2e+2]} share taps fe at offsets (e+1,e+2);
  //      a2[k]={w12[k],w12[k+1]} adjacent pairs ----
  for (int idx = tid; idx < 26 * 33; idx += 256) {
    int s = idx / 26, u = idx - 26 * s;
    const float* I1r = &I1[u * I1S];
    if (s < 32) {
      float w12[12];
      if (s == 0) {
        float4 qb = *(const float4*)&I1r[0];
        float4 qc = *(const float4*)&I1r[4];
        w12[0] = 0.f; w12[1] = 0.f; w12[2] = 0.f; w12[3] = 0.f;
        w12[4] = qb.x; w12[5] = qb.y; w12[6] = qb.z; w12[7] = qb.w;
        w12[8] = qc.x; w12[9] = qc.y; w12[10] = qc.z; w12[11] = qc.w;
      } else {
        int c0 = 4 * s;
        float4 qa = *(const float4*)&I1r[c0 - 4];
        float4 qb = *(const float4*)&I1r[c0];
        float4 qc = *(const float4*)&I1r[c0 + 4];
        w12[0] = qa.x; w12[1] = qa.y; w12[2] = qa.z; w12[3] = qa.w;
        w12[4] = qb.x; w12[5] = qb.y; w12[6] = qb.z; w12[7] = qb.w;
        w12[8] = qc.x; w12[9] = qc.y; w12[10] = qc.z; w12[11] = qc.w;
      }
      f32x2 a2[9];                         // a2[k-1] = {w12[k], w12[k+1]}, k=1..9
#pragma unroll
      for (int k = 1; k <= 9; ++k) a2[k - 1] = (f32x2){w12[k], w12[k + 1]};
      f32x2 pe0 = (f32x2)0.f, pe1 = (f32x2)0.f, po0 = (f32x2)0.f, po1 = (f32x2)0.f;
#pragma unroll
      for (int j = 0; j < 6; ++j) {
        pe0 += fe[j] * a2[j];              // {o0,o2}: offsets 1+j,2+j
        po0 += fo[j] * a2[j + 1];          // {o1,o3}: offsets 2+j,3+j
        pe1 += fe[j] * a2[j + 2];          // {o4,o6}: offsets 3+j,4+j
        po1 += fo[j] * a2[j + 3];          // {o5,o7}: offsets 4+j,5+j
      }
      float o[8] = {pe0.x, po0.x, pe0.y, po0.y, pe1.x, po1.x, pe1.y, po1.y};
#pragma unroll
      for (int e = 0; e < 8; ++e) {
        float a = o[e];
        float m = (a >= 0.f) ? kPos : kNeg;
        a *= m;
        o[e] = fminf(fmaxf(a, -256.f), 256.f);
      }
      *(float4*)&I2[u * I2S + 8 * s]     = make_float4(o[0], o[1], o[2], o[3]);
      *(float4*)&I2[u * I2S + 8 * s + 4] = make_float4(o[4], o[5], o[6], o[7]);
    } else {
      float4 qa = *(const float4*)&I1r[124];
      float4 qb = *(const float4*)&I1r[128];
      float w8[8] = {qa.x, qa.y, qa.z, qa.w, qb.x, qb.y, qb.z, qb.w};
      float q[4];
      q[0] = fe[0]*w8[1] + fe[1]*w8[2] + fe[2]*w8[3] + fe[3]*w8[4] + fe[4]*w8[5] + fe[5]*w8[6];
      q[1] = fo[0]*w8[2] + fo[1]*w8[3] + fo[2]*w8[4] + fo[3]*w8[5] + fo[4]*w8[6] + fo[5]*w8[7];
      q[2] = fe[0]*w8[2] + fe[1]*w8[3] + fe[2]*w8[4] + fe[3]*w8[5] + fe[4]*w8[6] + fe[5]*w8[7];
      q[3] = fo[0]*w8[3] + fo[1]*w8[4] + fo[2]*w8[5] + fo[3]*w8[6] + fo[4]*w8[7];
      float q2[4];
#pragma unroll
      for (int e = 0; e < 4; ++e) {
        float a = q[e];
        float m = (a >= 0.f) ? kPos : kNeg;
        a *= m;
        q2[e] = fminf(fmaxf(a, -256.f), 256.f);
      }
      *(float4*)&I2[u * I2S + 256] = make_float4(q2[0], q2[1], q2[2], q2[3]);
    }
  }
  __syncthreads();

  // ---- P3: vertical down-FIR -> D[y][v+5], packed row-pairs (windows shift by 2) ----
  {
    if (tid < 96) {
      int r = tid / 12, j = tid - 12 * r;
      int col = (j < 5) ? j : (260 + j);
      D[r * 272 + col] = 0.f;
    }
    auto p3col = [&](int v) {
      float wn[26];
#pragma unroll
      for (int t = 0; t < 26; ++t) wn[t] = I2[t * I2S + v];
      f32x2 s2[24];                        // s2[k] = {wn[k], wn[k+2]}
#pragma unroll
      for (int k = 0; k < 24; ++k) s2[k] = (f32x2){wn[k], wn[k + 2]};
#pragma unroll
      for (int yp = 0; yp < 4; ++yp) {     // pairs (2yp, 2yp+1)
        f32x2 a = (f32x2)0.f;
#pragma unroll
        for (int t = 0; t < 12; ++t) a += fdt[t] * s2[4 * yp + t];
        D[(2 * yp) * 272 + v + 5]     = a.x;
        D[(2 * yp + 1) * 272 + v + 5] = a.y;
      }
    };
    p3col(tid);
    if (tid < 4) p3col(256 + tid);
  }
  __syncthreads();

  // ---- P4: horizontal down-FIR -> global (float2 LDS reads) ----
  if (tid < 208) {
    int row = tid / 26, s4 = tid - 26 * row;
    int gy = y0 + row;
    if (gy < HO_) {
      float wn[20];
#pragma unroll
      for (int k = 0; k < 10; ++k) {
        float2 t2 = *(const float2*)&D[row * 272 + 10 * s4 + 2 * k];
        wn[2 * k] = t2.x;
        wn[2 * k + 1] = t2.y;
      }
      float* dp = dst + (size_t)plane * (HO_ * HO_) + gy * HO_ + 5 * s4;
#pragma unroll
      for (int q = 0; q < 5; ++q) {
        float a = 0.f;
#pragma unroll
        for (int t = 0; t < 12; ++t) a += fdt[t] * wn[2 * q + t];
        dp[q] = a;
      }
    }
  }
}

// ---------------- launch ----------------
extern "C" void kernel_launch(void* const* d_in, const int* in_sizes, int n_in,
                              void* d_out, int out_size, void* d_ws, size_t ws_size,
                              hipStream_t stream) {
  (void)in_sizes; (void)n_in; (void)out_size; (void)ws_size;
  const float* input  = (const float*)d_in[0];
  const float* style  = (const float*)d_in[1];
  const float* weight = (const float*)d_in[2];
  const float* mw     = (const float*)d_in[3];
  const float* mb     = (const float*)d_in[4];
  const float* bias   = (const float*)d_in[5];
  const float* upf    = (const float*)d_in[6];
  const float* dnf    = (const float*)d_in[7];
  float* out = (float*)d_out;

  float* out1   = (float*)d_ws;                               // 69.22 MB
  float* s      = out1 + (size_t)B_ * COUT_ * HO_ * HO_;      // [4][256]
  float* demod  = s + B_ * CIN_;                              // [4][256]
  ushort_t* Wth = (ushort_t*)(demod + B_ * COUT_);            // 1.18 MB
  float*    zp  = (float*)(Wth + 589824);                     // 16 B zero page
  ushort_t* Xt  = (ushort_t*)(zp + 4);                        // 32 MB (bf16)

  k_mod   <<<256, 256, 0, stream>>>(style, mw, mb, s);
  k_prep_x<<<dim3(256, 2, B_), 256, 0, stream>>>(input, s, Xt, zp);
  k_demod <<<256, 256, 0, stream>>>(weight, s, demod);
  k_prep_w<<<2304, 256, 0, stream>>>(weight, Wth);
  k_conv_mfma<<<dim3(9, 13, 8), 256, 0, stream>>>(Xt, Wth, demod, bias,
                                                  (const ushort_t*)zp, out1);
  k_fir   <<<dim3(17, 1024), 256, 0, stream>>>(out1, upf, dnf, out);
}

// Round 22
// 224.086 us; speedup vs baseline: 1.1844x; 1.0033x over previous
//
#include <hip/hip_runtime.h>
#include <hip/hip_bf16.h>
#include <math.h>

#define B_    4
#define CIN_  256
#define COUT_ 256
#define H_    128
#define W_    128
#define HW_   16384
#define SD_   512
#define HO_   130
#define HU_   260
#define NT_   12

typedef unsigned short ushort_t;
typedef __attribute__((ext_vector_type(8))) short short8;
typedef __attribute__((ext_vector_type(4))) float f32x4;
typedef __attribute__((ext_vector_type(2))) float f32x2;

__device__ inline ushort_t f2bf_(float v) {
  union { float f; unsigned u; } x; x.f = v;
  unsigned r = x.u + 0x7fffu + ((x.u >> 16) & 1u);
  return (ushort_t)(r >> 16);
}
__device__ inline void gll16(const ushort_t* g, ushort_t* l) {
  __builtin_amdgcn_global_load_lds(
      (const __attribute__((address_space(1))) unsigned int*)g,
      (__attribute__((address_space(3))) unsigned int*)l, 16, 0, 0);
}

// ---------------- K1: modulation s[b][cin] ----------------
__global__ __launch_bounds__(256) void k_mod(const float* __restrict__ style,
                                             const float* __restrict__ mw,
                                             const float* __restrict__ mb,
                                             float* __restrict__ s) {
  int wid  = (blockIdx.x * blockDim.x + threadIdx.x) >> 6;
  int lane = threadIdx.x & 63;
  int b = wid >> 8, ci = wid & 255;
  const float* st = style + b * SD_;
  const float* w  = mw + ci * SD_;
  float acc = 0.f;
  for (int k = lane; k < SD_; k += 64) acc += st[k] * w[k];
  for (int off = 32; off; off >>= 1) acc += __shfl_down(acc, off);
  if (lane == 0) s[wid] = acc * 0.044194173824159216f + mb[ci];
}

// ---------------- K2: demod[b][cout] ----------------
__global__ __launch_bounds__(256) void k_demod(const float* __restrict__ weight,
                                               const float* __restrict__ s,
                                               float* __restrict__ demod) {
  int wid  = (blockIdx.x * blockDim.x + threadIdx.x) >> 6;
  int lane = threadIdx.x & 63;
  int b = wid >> 8, co = wid & 255;
  const float* wrow = weight + co * CIN_ * 9;
  const float* sb   = s + b * CIN_;
  float acc = 0.f;
  for (int e = lane; e < CIN_ * 9; e += 64) {
    float p = wrow[e] * sb[e / 9];
    acc += p * p;
  }
  for (int off = 32; off; off >>= 1) acc += __shfl_down(acc, off);
  if (lane == 0) demod[wid] = rsqrtf(acc + 1e-8f);
}

// ---------------- K2b: weight pre-transform (bf16) ----------------
__global__ __launch_bounds__(256) void k_prep_w(const float* __restrict__ W,
                                                ushort_t* __restrict__ Wth) {
  int idx = blockIdx.x * 256 + threadIdx.x;
  if (idx >= 589824) return;
  int j  = idx & 7;
  int co = (idx >> 3) & 127;
  int kc = (idx >> 10) & 3;
  int kb = (idx >> 12) & 7;
  int cb = (idx >> 15) & 1;
  int t  = idx >> 16;
  int ci  = kb * 32 + kc * 8 + j;
  int cog = cb * 128 + co;
  Wth[idx] = f2bf_(W[(cog * CIN_ + ci) * 9 + t]);
}

// ---------------- K2c: X pre-transform (pure bf16) ----------------
__global__ __launch_bounds__(256) void k_prep_x(const float* __restrict__ input,
                                                const float* __restrict__ s,
                                                ushort_t* __restrict__ Xt,
                                                float* __restrict__ zp) {
  int b = blockIdx.z, cb = blockIdx.y, px0 = blockIdx.x * 64;
  int tid = threadIdx.x;
  __shared__ float T[64 * 131];
  __shared__ float sSh[128];
  if (tid < 128) sSh[tid] = s[b * 256 + cb * 128 + tid];
  if (blockIdx.x == 0 && blockIdx.y == 0 && blockIdx.z == 0 && tid < 4)
    zp[tid] = 0.f;
  __syncthreads();
  const float* inb = input + (size_t)(b * 256 + cb * 128) * HW_ + px0;
#pragma unroll
  for (int r2 = 0; r2 < 32; ++r2) {
    int idx = r2 * 256 + tid;
    int ci = idx >> 6, p = idx & 63;
    T[p * 131 + ci] = inb[(size_t)ci * HW_ + p] * sSh[ci];
  }
  __syncthreads();
  ushort_t* xb = Xt + (size_t)b * HW_ * 256 + cb * 128;
#pragma unroll
  for (int r2 = 0; r2 < 16; ++r2) {
    int u = r2 * 256 + tid;
    int cp = u & 63, p = u >> 6;
    float v0 = T[p * 131 + 2 * cp], v1 = T[p * 131 + 2 * cp + 1];
    unsigned pk = (unsigned)f2bf_(v0) | ((unsigned)f2bf_(v1) << 16);
    *(unsigned*)(xb + ((size_t)(px0 + p)) * 256 + cp * 2) = pk;
  }
}

// ---------------- K3: modulated conv via MFMA (X bf16, W bf16; 3 blocks/CU) ----------------
#define XCELLS 864
#define XROUNDS 4
#define XBUFU  1024

__global__ __launch_bounds__(256, 3) void k_conv_mfma(
    const ushort_t* __restrict__ Xt, const ushort_t* __restrict__ Wth,
    const float* __restrict__ demod, const float* __restrict__ bias,
    const ushort_t* __restrict__ zpg, float* __restrict__ out1) {
  const int tid = threadIdx.x;
  const int b = blockIdx.z >> 1, cb = blockIdx.z & 1;
  const int y0 = blockIdx.y * 10, x0 = blockIdx.x * 16;
  const int lane = tid & 63, lr = lane & 15, kcc = lane >> 4;
  const int w = tid >> 6;

  __shared__ __align__(16) ushort_t XL[2][XBUFU * 8];

  f32x4 acc[2][10];
#pragma unroll
  for (int i = 0; i < 2; ++i)
#pragma unroll
    for (int jj = 0; jj < 10; ++jj) acc[i][jj] = (f32x4)0.f;

  const ushort_t* gsrc[XROUNDS];
  bool okr[XROUNDS];
#pragma unroll
  for (int r = 0; r < XROUNDS; ++r) {
    int u = r * 256 + tid;
    const ushort_t* p = zpg;
    bool ok = false;
    if (u < XCELLS) {
      int kc = u / 216, cell = u - kc * 216;
      int hy = cell / 18, hx = cell - hy * 18;
      int iy = y0 + hy - 2, ix = x0 + hx - 2;
      if ((unsigned)iy < 128u && (unsigned)ix < 128u) {
        p = Xt + (((size_t)b * HW_ + iy * W_ + ix) << 8) + kc * 8;
        ok = true;
      }
    }
    gsrc[r] = p; okr[r] = ok;
  }

  auto stage = [&](int kb, int bufsel) {
    ushort_t* lb = &XL[bufsel][(size_t)tid * 8];
#pragma unroll
    for (int r = 0; r < XROUNDS; ++r) {
      const ushort_t* g = okr[r] ? gsrc[r] + kb * 32 : zpg;
      gll16(g, lb + r * 2048);
    }
  };

  stage(0, 0);
  __syncthreads();

  for (int kb = 0; kb < 8; ++kb) {
    const ushort_t* Xc = &XL[kb & 1][0];
    const int wbo = cb * 32768 + kb * 4096 + kcc * 1024 + (w * 32 + lr) * 8;
#pragma unroll
    for (int kx = 0; kx < 3; ++kx) {
      short8 ah[3][2];
#pragma unroll
      for (int ky = 0; ky < 3; ++ky) {
        const ushort_t* wh = Wth + wbo + (ky * 3 + kx) * 65536;
        ah[ky][0] = *(const short8*)wh;
        ah[ky][1] = *(const short8*)(wh + 128);
      }
      if (kx == 0) {
        __builtin_amdgcn_sched_barrier(0);
        if (kb < 7) stage(kb + 1, (kb & 1) ^ 1);
      }
#pragma unroll
      for (int r = 0; r < 12; ++r) {
        const int c16 = (kcc * 216 + r * 18 + lr + kx) * 8;
        short8 bh = *(const short8*)&Xc[c16];
#pragma unroll
        for (int ky = 0; ky < 3; ++ky) {
          const int bn = r - ky;
          if (bn >= 0 && bn < 10) {
            acc[0][bn] = __builtin_amdgcn_mfma_f32_16x16x32_bf16(ah[ky][0], bh, acc[0][bn], 0, 0, 0);
            acc[1][bn] = __builtin_amdgcn_mfma_f32_16x16x32_bf16(ah[ky][1], bh, acc[1][bn], 0, 0, 0);
          }
        }
      }
    }
    if (kb < 7) __syncthreads();
  }

#pragma unroll
  for (int am = 0; am < 2; ++am) {
#pragma unroll
    for (int r = 0; r < 4; ++r) {
      int cog = cb * 128 + w * 32 + am * 16 + kcc * 4 + r;
      float dm = demod[b * 256 + cog];
      float bv = bias[cog];
      int ox = x0 + lr;
      if (ox < HO_) {
#pragma unroll
        for (int bn = 0; bn < 10; ++bn) {
          int oy = y0 + bn;
          out1[((b * 256 + cog) * HO_ + oy) * HO_ + ox] = acc[am][bn][r] * dm + bv;
        }
      }
    }
  }
}

// ---------------- K4: fused FIR (R22: packed P1/P2/P3 + packed P4) ----------------
#define I1S 132
#define I2S 260

__global__ __launch_bounds__(256) void k_fir(const float* __restrict__ src,
                                             const float* __restrict__ upf,
                                             const float* __restrict__ dnf,
                                             float* __restrict__ dst) {
  const int plane = blockIdx.y;
  const int y0 = blockIdx.x * 8;
  const int tid = threadIdx.x;

  __shared__ __align__(16) float I1D[26 * I1S];   // I1 (P1->P2), then D 8x272 (P3->P4)
  __shared__ __align__(16) float B2[26 * I2S];    // SD 18x132 (P0->P1), then I2 (P2->P3)

  float* SD = B2;
  float* I2 = B2;
  float* I1 = I1D;
  float* D  = I1D;

  float fe[6], fo[6], fdt[12];
#pragma unroll
  for (int j = 0; j < 6; ++j) { fe[j] = upf[2 * j] * 2.f; fo[j] = upf[2 * j + 1] * 2.f; }
#pragma unroll
  for (int t = 0; t < NT_; ++t) fdt[t] = dnf[t];
  const float kPos = 1.41421356237309515f, kNeg = 0.28284271247461903f;

  // ---- P0: stage src rows [y0-5, y0+13) as float4 LDS writes ----
  const float* sp = src + (size_t)plane * (HO_ * HO_);
#pragma unroll
  for (int k = 0; k < 3; ++k) {
    int idx = tid + k * 256;
    if (idx < 594) {
      int r = idx / 33, q = idx - 33 * r;
      int gy = y0 - 5 + r;
      int cbase = 4 * q;
      float4 v = make_float4(0.f, 0.f, 0.f, 0.f);
      if ((unsigned)gy < (unsigned)HO_) {
        const float* rp = sp + gy * HO_ + cbase;
        v.x = rp[0];
        v.y = (cbase + 1 < HO_) ? rp[1] : 0.f;
        v.z = (cbase + 2 < HO_) ? rp[2] : 0.f;
        v.w = (cbase + 3 < HO_) ? rp[3] : 0.f;
      }
      *(float4*)&SD[r * 132 + cbase] = v;
    }
  }
  __syncthreads();

  // ---- P1: vertical up-FIR -> I1[u][c], packed pairs ----
  {
    int c = tid & 127, uh = tid >> 7;
    int base = uh ? 6 : 0;
    float rw[12];
#pragma unroll
    for (int j = 0; j < 12; ++j) rw[j] = SD[(base + j) * 132 + c];
    f32x2 fp2[6];
#pragma unroll
    for (int j = 0; j < 6; ++j) fp2[j] = (f32x2){fo[j], fe[j]};
    if (uh == 0) {
#pragma unroll
      for (int p = 0; p < 7; ++p) {
        f32x2 a = (f32x2)0.f;
#pragma unroll
        for (int j = 0; j < 6; ++j) a += fp2[j] * rw[p + j];
        int ug0 = 2 * y0 - 5 + 2 * p;
        int ug1 = 2 * y0 - 4 + 2 * p;
        I1[(2 * p) * I1S + c]     = ((unsigned)ug0 < (unsigned)HU_) ? a.x : 0.f;
        I1[(2 * p + 1) * I1S + c] = ((unsigned)ug1 < (unsigned)HU_) ? a.y : 0.f;
      }
    } else {
#pragma unroll
      for (int p = 7; p < 13; ++p) {
        f32x2 a = (f32x2)0.f;
#pragma unroll
        for (int j = 0; j < 6; ++j) a += fp2[j] * rw[p - 6 + j];
        int ug0 = 2 * y0 - 5 + 2 * p;
        int ug1 = 2 * y0 - 4 + 2 * p;
        I1[(2 * p) * I1S + c]     = ((unsigned)ug0 < (unsigned)HU_) ? a.x : 0.f;
        I1[(2 * p + 1) * I1S + c] = ((unsigned)ug1 < (unsigned)HU_) ? a.y : 0.f;
      }
    }
    if (tid >= 200 && tid < 252) {
      int t2 = tid - 200;
      int c2 = 128 + (t2 & 1), u2 = t2 >> 1;
      float a = 0.f;
      if ((u2 & 1) == 0) {
        int lr = u2 >> 1;
#pragma unroll
        for (int j = 0; j < 6; ++j) a += fo[j] * SD[(lr + j) * 132 + c2];
      } else {
        int lr = (u2 - 1) >> 1;
#pragma unroll
        for (int j = 0; j < 6; ++j) a += fe[j] * SD[(lr + j) * 132 + c2];
      }
      int ugl = 2 * y0 - 5 + u2;
      I1[u2 * I1S + c2] = ((unsigned)ugl < (unsigned)HU_) ? a : 0.f;
    }
    if (tid < 52) {
      int r = tid >> 1, col = 130 + (tid & 1);
      I1[r * I1S + col] = 0.f;
    }
  }
  __syncthreads();

  // ---- P2: horizontal up-FIR + lrelu + clamp -> I2[u][v] (packed) ----
  for (int idx = tid; idx < 26 * 33; idx += 256) {
    int s = idx / 26, u = idx - 26 * s;
    const float* I1r = &I1[u * I1S];
    if (s < 32) {
      float w12[12];
      if (s == 0) {
        float4 qb = *(const float4*)&I1r[0];
        float4 qc = *(const float4*)&I1r[4];
        w12[0] = 0.f; w12[1] = 0.f; w12[2] = 0.f; w12[3] = 0.f;
        w12[4] = qb.x; w12[5] = qb.y; w12[6] = qb.z; w12[7] = qb.w;
        w12[8] = qc.x; w12[9] = qc.y; w12[10] = qc.z; w12[11] = qc.w;
      } else {
        int c0 = 4 * s;
        float4 qa = *(const float4*)&I1r[c0 - 4];
        float4 qb = *(const float4*)&I1r[c0];
        float4 qc = *(const float4*)&I1r[c0 + 4];
        w12[0] = qa.x; w12[1] = qa.y; w12[2] = qa.z; w12[3] = qa.w;
        w12[4] = qb.x; w12[5] = qb.y; w12[6] = qb.z; w12[7] = qb.w;
        w12[8] = qc.x; w12[9] = qc.y; w12[10] = qc.z; w12[11] = qc.w;
      }
      f32x2 a2[9];
#pragma unroll
      for (int k = 1; k <= 9; ++k) a2[k - 1] = (f32x2){w12[k], w12[k + 1]};
      f32x2 pe0 = (f32x2)0.f, pe1 = (f32x2)0.f, po0 = (f32x2)0.f, po1 = (f32x2)0.f;
#pragma unroll
      for (int j = 0; j < 6; ++j) {
        pe0 += fe[j] * a2[j];
        po0 += fo[j] * a2[j + 1];
        pe1 += fe[j] * a2[j + 2];
        po1 += fo[j] * a2[j + 3];
      }
      float o[8] = {pe0.x, po0.x, pe0.y, po0.y, pe1.x, po1.x, pe1.y, po1.y};
#pragma unroll
      for (int e = 0; e < 8; ++e) {
        float a = o[e];
        float m = (a >= 0.f) ? kPos : kNeg;
        a *= m;
        o[e] = fminf(fmaxf(a, -256.f), 256.f);
      }
      *(float4*)&I2[u * I2S + 8 * s]     = make_float4(o[0], o[1], o[2], o[3]);
      *(float4*)&I2[u * I2S + 8 * s + 4] = make_float4(o[4], o[5], o[6], o[7]);
    } else {
      float4 qa = *(const float4*)&I1r[124];
      float4 qb = *(const float4*)&I1r[128];
      float w8[8] = {qa.x, qa.y, qa.z, qa.w, qb.x, qb.y, qb.z, qb.w};
      float q[4];
      q[0] = fe[0]*w8[1] + fe[1]*w8[2] + fe[2]*w8[3] + fe[3]*w8[4] + fe[4]*w8[5] + fe[5]*w8[6];
      q[1] = fo[0]*w8[2] + fo[1]*w8[3] + fo[2]*w8[4] + fo[3]*w8[5] + fo[4]*w8[6] + fo[5]*w8[7];
      q[2] = fe[0]*w8[2] + fe[1]*w8[3] + fe[2]*w8[4] + fe[3]*w8[5] + fe[4]*w8[6] + fe[5]*w8[7];
      q[3] = fo[0]*w8[3] + fo[1]*w8[4] + fo[2]*w8[5] + fo[3]*w8[6] + fo[4]*w8[7];
      float q2[4];
#pragma unroll
      for (int e = 0; e < 4; ++e) {
        float a = q[e];
        float m = (a >= 0.f) ? kPos : kNeg;
        a *= m;
        q2[e] = fminf(fmaxf(a, -256.f), 256.f);
      }
      *(float4*)&I2[u * I2S + 256] = make_float4(q2[0], q2[1], q2[2], q2[3]);
    }
  }
  __syncthreads();

  // ---- P3: vertical down-FIR -> D[y][v+5], packed row-pairs ----
  {
    if (tid < 96) {
      int r = tid / 12, j = tid - 12 * r;
      int col = (j < 5) ? j : (260 + j);
      D[r * 272 + col] = 0.f;
    }
    auto p3col = [&](int v) {
      float wn[26];
#pragma unroll
      for (int t = 0; t < 26; ++t) wn[t] = I2[t * I2S + v];
      f32x2 s2[24];
#pragma unroll
      for (int k = 0; k < 24; ++k) s2[k] = (f32x2){wn[k], wn[k + 2]};
#pragma unroll
      for (int yp = 0; yp < 4; ++yp) {
        f32x2 a = (f32x2)0.f;
#pragma unroll
        for (int t = 0; t < 12; ++t) a += fdt[t] * s2[4 * yp + t];
        D[(2 * yp) * 272 + v + 5]     = a.x;
        D[(2 * yp + 1) * 272 + v + 5] = a.y;
      }
    };
    p3col(tid);
    if (tid < 4) p3col(256 + tid);
  }
  __syncthreads();

  // ---- P4: horizontal down-FIR -> global (packed output pairs) ----
  if (tid < 208) {
    int row = tid / 26, s4 = tid - 26 * row;
    int gy = y0 + row;
    if (gy < HO_) {
      float wn[20];
#pragma unroll
      for (int k = 0; k < 10; ++k) {
        float2 t2 = *(const float2*)&D[row * 272 + 10 * s4 + 2 * k];
        wn[2 * k] = t2.x;
        wn[2 * k + 1] = t2.y;
      }
      float* dp = dst + (size_t)plane * (HO_ * HO_) + gy * HO_ + 5 * s4;
      f32x2 s2[16];
#pragma unroll
      for (int k = 0; k < 16; ++k) s2[k] = (f32x2){wn[k], wn[k + 2]};
#pragma unroll
      for (int qp = 0; qp < 2; ++qp) {     // output pairs (0,1),(2,3)
        f32x2 a = (f32x2)0.f;
#pragma unroll
        for (int t = 0; t < 12; ++t) a += fdt[t] * s2[4 * qp + t];
        dp[2 * qp]     = a.x;
        dp[2 * qp + 1] = a.y;
      }
      float a4 = 0.f;
#pragma unroll
      for (int t = 0; t < 12; ++t) a4 += fdt[t] * wn[8 + t];
      dp[4] = a4;
    }
  }
}

// ---------------- launch ----------------
extern "C" void kernel_launch(void* const* d_in, const int* in_sizes, int n_in,
                              void* d_out, int out_size, void* d_ws, size_t ws_size,
                              hipStream_t stream) {
  (void)in_sizes; (void)n_in; (void)out_size; (void)ws_size;
  const float* input  = (const float*)d_in[0];
  const float* style  = (const float*)d_in[1];
  const float* weight = (const float*)d_in[2];
  const float* mw     = (const float*)d_in[3];
  const float* mb     = (const float*)d_in[4];
  const float* bias   = (const float*)d_in[5];
  const float* upf    = (const float*)d_in[6];
  const float* dnf    = (const float*)d_in[7];
  float* out = (float*)d_out;

  float* out1   = (float*)d_ws;                               // 69.22 MB
  float* s      = out1 + (size_t)B_ * COUT_ * HO_ * HO_;      // [4][256]
  float* demod  = s + B_ * CIN_;                              // [4][256]
  ushort_t* Wth = (ushort_t*)(demod + B_ * COUT_);            // 1.18 MB
  float*    zp  = (float*)(Wth + 589824);                     // 16 B zero page
  ushort_t* Xt  = (ushort_t*)(zp + 4);                        // 32 MB (bf16)

  k_mod   <<<256, 256, 0, stream>>>(style, mw, mb, s);
  k_prep_x<<<dim3(256, 2, B_), 256, 0, stream>>>(input, s, Xt, zp);
  k_demod <<<256, 256, 0, stream>>>(weight, s, demod);
  k_prep_w<<<2304, 256, 0, stream>>>(weight, Wth);
  k_conv_mfma<<<dim3(9, 13, 8), 256, 0, stream>>>(Xt, Wth, demod, bias,
                                                  (const ushort_t*)zp, out1);
  k_fir   <<<dim3(17, 1024), 256, 0, stream>>>(out1, upf, dnf, out);
}